// Round 6
// baseline (158.949 us; speedup 1.0000x reference)
//
#include <hip/hip_runtime.h>
#include <hip/hip_bf16.h>

#define SELF_D 36
#define ENT_D  28
#define HID    256
#define OBS    1688   // 36 + 28*59
#define NWAVES 8192   // pool: 2048 blocks x 4 waves, wave-per-row

// ws float layout
#define WS_A     0        // 36*256 (k-major)
#define WS_B     9216     // 28*256
#define WS_C     16384    // 256
#define WS_MSEL  16640    // 108  } contiguous 360 = Mfull[120][3]
#define WS_MENT  16748    // 252
#define WS_CG    17000    // 3
#define WS_WATT  17008    // 28
#define WS_AT    17040    // 256*36 c-major AT[c][k]
#define WS_BT    26256    // 256*28 c-major BT[c][k]
#define WS_TOTAL 33424

__global__ __launch_bounds__(256)
void setup_kernel(const float* __restrict__ Watt, const float* __restrict__ We,
                  const float* __restrict__ be,  const float* __restrict__ Wse,
                  const float* __restrict__ bse, const float* __restrict__ Wg,
                  const float* __restrict__ bg,  const float* __restrict__ Wo,
                  const float* __restrict__ bo,  float* __restrict__ ws) {
  const int blk = blockIdx.x;
  const int c = threadIdx.x;
  if (blk < 36) {
    int k = blk;
    float acc = 0.f;
    for (int r = 0; r < 256; ++r) acc += We[k*256 + r] * Wo[r*256 + c];
    for (int r = 0; r < 256; ++r) acc += (Wse[k*256 + r] + Wse[(36+k)*256 + r]) * Wo[(256+r)*256 + c];
    ws[WS_A + k*256 + c] = acc;
    ws[WS_AT + c*36 + k] = acc;
  } else if (blk < 64) {
    int k = blk - 36;
    float acc = 0.f;
    for (int r = 0; r < 256; ++r) acc += We[(36+k)*256 + r] * Wo[r*256 + c];
    ws[WS_B + k*256 + c] = acc;
    ws[WS_BT + c*28 + k] = acc;
  } else if (blk == 64) {
    float acc = bo[c];
    for (int r = 0; r < 256; ++r) acc += be[r] * Wo[r*256 + c];
    for (int r = 0; r < 256; ++r) acc += bse[r] * Wo[(256+r)*256 + c];
    ws[WS_C + c] = acc;
  } else {
    for (int t = c; t < 391; t += 256) {
      if (t < 108) {
        int k = t / 3, j = t - 3*k;
        float acc = 0.f;
        for (int r = 0; r < 256; ++r) {
          float wg = Wg[r*3 + j] + Wg[(256+r)*3 + j] + Wg[(512+r)*3 + j];
          acc += We[k*256 + r] * wg;
        }
        ws[WS_MSEL + t] = acc;
      } else if (t < 360) {
        int idx = t - 108;
        int g = idx / 84, rem = idx - 84*g;
        int k = rem / 3, j = rem - 3*k;
        float acc = 0.f;
        for (int r = 0; r < 256; ++r) acc += We[(36+k)*256 + r] * Wg[(256*g + r)*3 + j];
        ws[WS_MENT + idx] = acc;
      } else if (t < 363) {
        int j = t - 360;
        float acc = bg[j];
        for (int r = 0; r < 256; ++r)
          acc += be[r] * (Wg[r*3 + j] + Wg[(256+r)*3 + j] + Wg[(512+r)*3 + j]);
        ws[WS_CG + j] = acc;
      } else {
        int k = t - 363;
        ws[WS_WATT + k] = Watt[36 + k];
      }
    }
  }
}

// Wave-per-row, per-wave LDS tile. Pipeline (T14): issue next-row loads to
// regs at iter top; compute current row from LDS; regs -> LDS at iter bottom.
// Compiler inserts vmcnt for pf uses and lgkm for tile RAW; only the prologue
// global_load_lds needs a manual vmcnt (+sched_barrier, rule #18).
// Slots: slot = g*20 + i; slot 39 is DUMMY (par has 19); ent = slot - (slot>=40).
__global__ __launch_bounds__(256)
void pool_kernel(const float* __restrict__ x, const float* __restrict__ ws,
                 float* __restrict__ out, int B) {
  __shared__ __align__(16) float tile[4][OBS];   // 27008 B, row per wave
  __shared__ __align__(16) float satt[4][64];
  __shared__ __align__(16) float sebar[4][84];
  __shared__ __align__(16) float sW[28];
  __shared__ __align__(16) float sM[360];        // Mfull[120][3]

  const int tid = threadIdx.x;
  const int w = tid >> 6, ln = tid & 63;

  for (int t = tid; t < 360; t += 256) sM[t] = ws[WS_MSEL + t];
  if (tid < 28) sW[tid] = ws[WS_WATT + tid];
  __syncthreads();                               // one-time init fence

  const float cg0 = ws[WS_CG + 0], cg1 = ws[WS_CG + 1], cg2 = ws[WS_CG + 2];

  const int ent_b  = ln - (ln >= 40 ? 1 : 0);
  const bool valid = (ln < 60) && (ln != 39);
  const int ent_r  = valid ? ent_b : 0;
  const int gj = ln >> 4, gch = ln & 15;
  const bool gact = (gj < 3) && (gch < 15);

  const int row0 = blockIdx.x * 4 + w;

  // prologue: stage first row straight into LDS (coalesced 1KB bursts)
  if (row0 < B) {
    const float* xr = x + (size_t)row0 * OBS;
#pragma unroll
    for (int i = 0; i < 7; ++i) {
      int idx = i * 64 + ln;
      if (idx < OBS / 4) {
        __builtin_amdgcn_global_load_lds(
            (const __attribute__((address_space(1))) void*)(xr + idx * 4),
            (__attribute__((address_space(3))) void*)(&tile[w][0] + idx * 4),
            16, 0, 0);
      }
    }
  }

  for (int row = row0; row < B; row += NWAVES) {
    const bool pfv = (row + NWAVES) < B;

    // issue next row's loads into registers (in flight across compute)
    float4 pf[7];
    if (pfv) {
      const float4* xn = (const float4*)(x + (size_t)(row + NWAVES) * OBS);
#pragma unroll
      for (int i = 0; i < 7; ++i) {
        int idx = i * 64 + ln;
        if (idx < OBS / 4) pf[i] = xn[idx];
      }
    }

    if (row == row0) {  // gate only the prologue's lds-loads
      if (pfv) asm volatile("s_waitcnt vmcnt(7)" ::: "memory");
      else     asm volatile("s_waitcnt vmcnt(0)" ::: "memory");
      __builtin_amdgcn_sched_barrier(0);
    }

    // --- attention logits: lane = slot; plain chunk order (bank-uniform) ---
    float l = -1e30f;
    {
      const float4* ep = (const float4*)&tile[w][SELF_D + ENT_D * ent_r];
      const float4* w4 = (const float4*)sW;
      float acc = 0.f;
#pragma unroll
      for (int t = 0; t < 7; ++t) {
        float4 v = ep[t], wv = w4[t];
        acc += v.x*wv.x + v.y*wv.y + v.z*wv.z + v.w*wv.w;
      }
      if (valid) l = acc;
    }
    float m = l;
#pragma unroll
    for (int off = 32; off; off >>= 1) m = fmaxf(m, __shfl_xor(m, off));
    satt[w][ln] = valid ? __expf(l - m) : 0.f;

    // --- per-(g,k) weighted means: 84 tasks in 2 passes ---
#pragma unroll
    for (int pass = 0; pass < 2; ++pass) {
      int t = ln + pass * 64;
      if (t < 84) {
        int g = t / 28, k = t - 28 * g;
        int e0 = g * 20 - (g >> 1);              // 0, 20, 39
        const float* vb = &tile[w][SELF_D + ENT_D * e0 + k];
        const float* pa = &satt[w][g * 20];
        float us = 0.f, uv = 0.f;
#pragma unroll
        for (int i = 0; i < 20; ++i) {
          float pp = pa[i];
          float vv = vb[ENT_D * i];
          us += pp; uv += pp * vv;
        }
        sebar[w][t] = uv / us;
      }
    }

    // --- gate logits ---
    float gl = 0.f;
    if (gact) {
#pragma unroll
      for (int q = 0; q < 8; ++q) {
        int c = q * 15 + gch;
        float v = (c < SELF_D) ? tile[w][c] : sebar[w][c - SELF_D];
        gl += v * sM[c * 3 + gj];
      }
    }
#pragma unroll
    for (int off = 1; off < 16; off <<= 1) gl += __shfl_xor(gl, off);
    float l0 = __shfl(gl, 0)  + cg0;
    float l1 = __shfl(gl, 16) + cg1;
    float l2 = __shfl(gl, 32) + cg2;
    float mm = fmaxf(l0, fmaxf(l1, l2));
    float e0x = __expf(l0 - mm), e1x = __expf(l1 - mm), e2x = __expf(l2 - mm);
    float inv = 1.f / (e0x + e1x + e2x);

    // --- f value (read tile BEFORE overwrite) ---
    float fv;
    if (ln < SELF_D) {
      fv = tile[w][ln];
    } else {
      int k = ln - SELF_D;
      fv = (e0x * sebar[w][k] + e1x * sebar[w][28 + k] + e2x * sebar[w][56 + k]) * inv;
    }

    // --- regs -> LDS for next row (compiler adds vmcnt for pf, lgkm for RAW) ---
    if (pfv) {
      float4* dst = (float4*)&tile[w][0];
#pragma unroll
      for (int i = 0; i < 7; ++i) {
        int idx = i * 64 + ln;
        if (idx < OBS / 4) dst[idx] = pf[i];
      }
    }

    out[(size_t)row * HID + ln] = fv;
  }
}

// out[row][c] = cc[c] + f[0:36]@AT[c] + f[36:64]@BT[c]; f in-place from out[row][0:64].
#define PR_ROWS 32
#define PR_CH   8
__global__ __launch_bounds__(256)
void proj_kernel(const float* __restrict__ ws, float* __restrict__ out) {
  __shared__ __align__(16) float sf[PR_CH][64];
  const int tid = threadIdx.x;

  float4 Av[9], Bv[7];
#pragma unroll
  for (int q = 0; q < 9; ++q) Av[q] = ((const float4*)(ws + WS_AT + tid * 36))[q];
#pragma unroll
  for (int q = 0; q < 7; ++q) Bv[q] = ((const float4*)(ws + WS_BT + tid * 28))[q];
  const float cc = ws[WS_C + tid];

  const size_t row0 = (size_t)blockIdx.x * PR_ROWS;
  for (int chk = 0; chk < PR_ROWS / PR_CH; ++chk) {
    const size_t rbase = row0 + chk * PR_CH;
    if (tid < PR_CH * 16) {
      int r = tid >> 4, q = tid & 15;
      ((float4*)&sf[r][0])[q] = ((const float4*)(out + (rbase + r) * HID))[q];
    }
    __syncthreads();
#pragma unroll
    for (int r = 0; r < PR_CH; ++r) {
      float acc = cc;
      const float4* f4 = (const float4*)&sf[r][0];
#pragma unroll
      for (int q = 0; q < 9; ++q) {
        float4 s = f4[q];
        acc += Av[q].x*s.x + Av[q].y*s.y + Av[q].z*s.z + Av[q].w*s.w;
      }
#pragma unroll
      for (int q = 0; q < 7; ++q) {
        float4 s = f4[9 + q];
        acc += Bv[q].x*s.x + Bv[q].y*s.y + Bv[q].z*s.z + Bv[q].w*s.w;
      }
      out[(rbase + r) * HID + tid] = acc;
    }
    __syncthreads();
  }
}

extern "C" void kernel_launch(void* const* d_in, const int* in_sizes, int n_in,
                              void* d_out, int out_size, void* d_ws, size_t ws_size,
                              hipStream_t stream) {
  const float* x    = (const float*)d_in[0];
  const float* Watt = (const float*)d_in[1];
  const float* We   = (const float*)d_in[3];
  const float* be   = (const float*)d_in[4];
  const float* Wse  = (const float*)d_in[5];
  const float* bse  = (const float*)d_in[6];
  const float* Wg   = (const float*)d_in[7];
  const float* bg   = (const float*)d_in[8];
  const float* Wo   = (const float*)d_in[9];
  const float* bo   = (const float*)d_in[10];
  float* out = (float*)d_out;
  float* ws  = (float*)d_ws;
  const int B = in_sizes[0] / OBS;

  setup_kernel<<<66, 256, 0, stream>>>(Watt, We, be, Wse, bse, Wg, bg, Wo, bo, ws);
  pool_kernel<<<NWAVES / 4, 256, 0, stream>>>(x, ws, out, B);
  proj_kernel<<<B / PR_ROWS, 256, 0, stream>>>(ws, out);
}

// Round 8
// 106.911 us; speedup vs baseline: 1.4867x; 1.4867x over previous
//
#include <hip/hip_runtime.h>
#include <hip/hip_bf16.h>

#define SELF_D 36
#define ENT_D  28
#define HID    256
#define OBS    1688   // 36 + 28*59 ; 422 float4s
#define NWAVES 8192   // pool: 2048 blocks x 4 waves, wave-per-row
#define ETS    61     // transposed entity tile row stride (floats), odd => banks spread

// ws float layout
#define WS_A     0        // 36*256 (k-major)
#define WS_B     9216     // 28*256
#define WS_C     16384    // 256
#define WS_MSEL  16640    // 108  } contiguous 360 = Mfull[120][3]
#define WS_MENT  16748    // 252
#define WS_CG    17000    // 3
#define WS_WATT  17008    // 28
#define WS_AT    17040    // 256*36 c-major AT[c][k]
#define WS_BT    26256    // 256*28 c-major BT[c][k]
#define WS_TOTAL 33424

__global__ __launch_bounds__(256)
void setup_kernel(const float* __restrict__ Watt, const float* __restrict__ We,
                  const float* __restrict__ be,  const float* __restrict__ Wse,
                  const float* __restrict__ bse, const float* __restrict__ Wg,
                  const float* __restrict__ bg,  const float* __restrict__ Wo,
                  const float* __restrict__ bo,  float* __restrict__ ws) {
  const int blk = blockIdx.x;
  const int c = threadIdx.x;
  if (blk < 36) {
    int k = blk;
    float acc = 0.f;
    for (int r = 0; r < 256; ++r) acc += We[k*256 + r] * Wo[r*256 + c];
    for (int r = 0; r < 256; ++r) acc += (Wse[k*256 + r] + Wse[(36+k)*256 + r]) * Wo[(256+r)*256 + c];
    ws[WS_A + k*256 + c] = acc;
    ws[WS_AT + c*36 + k] = acc;
  } else if (blk < 64) {
    int k = blk - 36;
    float acc = 0.f;
    for (int r = 0; r < 256; ++r) acc += We[(36+k)*256 + r] * Wo[r*256 + c];
    ws[WS_B + k*256 + c] = acc;
    ws[WS_BT + c*28 + k] = acc;
  } else if (blk == 64) {
    float acc = bo[c];
    for (int r = 0; r < 256; ++r) acc += be[r] * Wo[r*256 + c];
    for (int r = 0; r < 256; ++r) acc += bse[r] * Wo[(256+r)*256 + c];
    ws[WS_C + c] = acc;
  } else {
    for (int t = c; t < 391; t += 256) {
      if (t < 108) {
        int k = t / 3, j = t - 3*k;
        float acc = 0.f;
        for (int r = 0; r < 256; ++r) {
          float wg = Wg[r*3 + j] + Wg[(256+r)*3 + j] + Wg[(512+r)*3 + j];
          acc += We[k*256 + r] * wg;
        }
        ws[WS_MSEL + t] = acc;
      } else if (t < 360) {
        int idx = t - 108;
        int g = idx / 84, rem = idx - 84*g;
        int k = rem / 3, j = rem - 3*k;
        float acc = 0.f;
        for (int r = 0; r < 256; ++r) acc += We[(36+k)*256 + r] * Wg[(256*g + r)*3 + j];
        ws[WS_MENT + idx] = acc;
      } else if (t < 363) {
        int j = t - 360;
        float acc = bg[j];
        for (int r = 0; r < 256; ++r)
          acc += be[r] * (Wg[r*3 + j] + Wg[(256+r)*3 + j] + Wg[(512+r)*3 + j]);
        ws[WS_CG + j] = acc;
      } else {
        int k = t - 363;
        ws[WS_WATT + k] = Watt[36 + k];
      }
    }
  }
}

// Wave-per-row. Entity block stored TRANSPOSED in per-wave LDS: ET[k][slot],
// stride ETS=61. Slots: slot = g*20 + i; slot 39 = DUMMY (zeroed once; satt=0).
// Per row: {pf regs -> LDS (transposing writes); issue next row's loads into pf;
// compute}. Empty-asm fences = compile-time ordering only (DS is in-order per
// wave in HW); no hardware waits in the loop.
__global__ __launch_bounds__(256)
void pool_kernel(const float* __restrict__ x, const float* __restrict__ ws,
                 float* __restrict__ out, int B) {
  __shared__ __align__(16) float ET[4][28*ETS + 4];  // ~27.4 KB
  __shared__ __align__(16) float sself[4][40];
  __shared__ __align__(16) float satt[4][64];
  __shared__ __align__(16) float sebar[4][88];
  __shared__ __align__(16) float sM[360];            // Mfull[120][3]

  const int tid = threadIdx.x;
  const int w = tid >> 6, ln = tid & 63;

  for (int t = tid; t < 360; t += 256) sM[t] = ws[WS_MSEL + t];
  if (ln < 28) ET[w][ln*ETS + 39] = 0.f;             // dummy column: never written again
  __syncthreads();                                   // one-time init fence

  const float* Wp = ws + WS_WATT;                    // uniform -> s_loads
  const float cg0 = ws[WS_CG + 0], cg1 = ws[WS_CG + 1], cg2 = ws[WS_CG + 2];

  // ---- row-invariant per-lane addressing ----
  int  eoff[7];
  bool went[7];
#pragma unroll
  for (int i = 0; i < 7; ++i) {
    int q = i*64 + ln;                 // flat float4 index in the row
    went[i] = (q >= 9) && (q < 422);   // entity chunks
    int e = (q - 9) / 7, t = (q - 9) % 7;
    int s = e + (e >= 39 ? 1 : 0);     // slot (skip dummy 39)
    eoff[i] = t*4*ETS + s;             // ET[w][4t + j][s] at +j*ETS
  }
  const bool wself0 = (ln < 9);        // i==0, q=ln<9 -> self float4s

  const bool lval = (ln < 60) && (ln != 39);
  const int  lcol = lval ? ln : 0;     // logit column = slot

  // mean-pass task split: pass0 = task ln (all lanes), pass1 = task ln+64 (ln<20)
  const int  mg0 = ln / 28, mk0 = ln - 28*mg0;       // ln<64 -> g in {0,1,2}
  const int  base0 = mk0*ETS + mg0*20;
  const bool mv1 = (ln < 20);                        // tasks 64..83: g=2, k=ln+8
  const int  base1 = (ln + 8)*ETS + 40;

  const int  gj = ln >> 4, gch = ln & 15;
  const bool gact = (gj < 3) && (gch < 15);

  const int row0 = blockIdx.x * 4 + w;

  // prologue: first row into pf registers (coalesced float4)
  float4 pf[7];
  if (row0 < B) {
    const float4* xr = (const float4*)(x + (size_t)row0 * OBS);
#pragma unroll
    for (int i = 0; i < 7; ++i) { int idx = i*64 + ln; if (idx < 422) pf[i] = xr[idx]; }
  }

  for (int row = row0; row < B; row += NWAVES) {
    // (1) pf -> LDS, transposing entity chunks (compiler waits pf's vmcnt here)
    if (wself0) *(float4*)&sself[w][ln*4] = pf[0];
#pragma unroll
    for (int i = 0; i < 7; ++i) {
      if (went[i]) {
        float* p = &ET[w][eoff[i]];
        p[0]     = pf[i].x;
        p[ETS]   = pf[i].y;
        p[2*ETS] = pf[i].z;
        p[3*ETS] = pf[i].w;
      }
    }

    // (2) issue next row's loads into pf (fly across compute below; WAR-safe)
    {
      int nr = row + NWAVES;
      if (nr < B) {
        const float4* xn = (const float4*)(x + (size_t)nr * OBS);
#pragma unroll
        for (int i = 0; i < 7; ++i) { int idx = i*64 + ln; if (idx < 422) pf[i] = xn[idx]; }
      }
    }
    asm volatile("" ::: "memory");     // order (1) writes before (3)/(4) reads

    // (3) attention logits: lane = slot, conflict-free column scan
    float l = -1e30f;
    {
      const float* cb = &ET[w][lcol];
      float acc = 0.f;
#pragma unroll
      for (int k = 0; k < 28; ++k) acc += cb[k*ETS] * Wp[k];
      if (lval) l = acc;
    }
    float m = l;
#pragma unroll
    for (int off = 32; off; off >>= 1) m = fmaxf(m, __shfl_xor(m, off));
    satt[w][ln] = lval ? __expf(l - m) : 0.f;
    asm volatile("" ::: "memory");     // order satt write before (4) reads

    // (4) weighted means: 84 tasks in 2 passes, row scans of ET
    {
      const float* vb = &ET[w][base0];
      const float* pa = &satt[w][mg0 * 20];
      float us = 0.f, uv = 0.f;
#pragma unroll
      for (int i = 0; i < 20; ++i) { float pp = pa[i]; us += pp; uv += pp * vb[i]; }
      sebar[w][ln] = uv / us;          // task ln = g*28 + k
    }
    if (mv1) {
      const float* vb = &ET[w][base1];
      const float* pa = &satt[w][40];
      float us = 0.f, uv = 0.f;
#pragma unroll
      for (int i = 0; i < 20; ++i) { float pp = pa[i]; us += pp; uv += pp * vb[i]; }
      sebar[w][ln + 64] = uv / us;     // tasks 64..83
    }
    asm volatile("" ::: "memory");     // order sebar writes before (5)/(6) reads

    // (5) gate logits: lanes (j, ch), c = q*15 + ch over 120
    float gl = 0.f;
    if (gact) {
#pragma unroll
      for (int q = 0; q < 8; ++q) {
        int c = q*15 + gch;
        float v = (c < SELF_D) ? sself[w][c] : sebar[w][c - SELF_D];
        gl += v * sM[c*3 + gj];
      }
    }
#pragma unroll
    for (int off = 1; off < 16; off <<= 1) gl += __shfl_xor(gl, off);
    float l0 = __shfl(gl, 0)  + cg0;
    float l1 = __shfl(gl, 16) + cg1;
    float l2 = __shfl(gl, 32) + cg2;
    float mm = fmaxf(l0, fmaxf(l1, l2));
    float e0x = __expf(l0 - mm), e1x = __expf(l1 - mm), e2x = __expf(l2 - mm);
    float inv = 1.f / (e0x + e1x + e2x);

    // (6) emit f = [self(36), gated-mix(28)]
    float fv;
    if (ln < SELF_D) {
      fv = sself[w][ln];
    } else {
      int k = ln - SELF_D;
      fv = (e0x * sebar[w][k] + e1x * sebar[w][28 + k] + e2x * sebar[w][56 + k]) * inv;
    }
    out[(size_t)row * HID + ln] = fv;
  }
}

// out[row][c] = cc[c] + f[0:36]@AT[c] + f[36:64]@BT[c]; f in-place from out[row][0:64].
#define PR_ROWS 32
#define PR_CH   8
__global__ __launch_bounds__(256)
void proj_kernel(const float* __restrict__ ws, float* __restrict__ out) {
  __shared__ __align__(16) float sf[PR_CH][64];
  const int tid = threadIdx.x;

  float4 Av[9], Bv[7];
#pragma unroll
  for (int q = 0; q < 9; ++q) Av[q] = ((const float4*)(ws + WS_AT + tid * 36))[q];
#pragma unroll
  for (int q = 0; q < 7; ++q) Bv[q] = ((const float4*)(ws + WS_BT + tid * 28))[q];
  const float cc = ws[WS_C + tid];

  const size_t row0 = (size_t)blockIdx.x * PR_ROWS;
  for (int chk = 0; chk < PR_ROWS / PR_CH; ++chk) {
    const size_t rbase = row0 + chk * PR_CH;
    if (tid < PR_CH * 16) {
      int r = tid >> 4, q = tid & 15;
      ((float4*)&sf[r][0])[q] = ((const float4*)(out + (rbase + r) * HID))[q];
    }
    __syncthreads();
#pragma unroll
    for (int r = 0; r < PR_CH; ++r) {
      float acc = cc;
      const float4* f4 = (const float4*)&sf[r][0];
#pragma unroll
      for (int q = 0; q < 9; ++q) {
        float4 s = f4[q];
        acc += Av[q].x*s.x + Av[q].y*s.y + Av[q].z*s.z + Av[q].w*s.w;
      }
#pragma unroll
      for (int q = 0; q < 7; ++q) {
        float4 s = f4[9 + q];
        acc += Bv[q].x*s.x + Bv[q].y*s.y + Bv[q].z*s.z + Bv[q].w*s.w;
      }
      out[(rbase + r) * HID + tid] = acc;
    }
    __syncthreads();
  }
}

extern "C" void kernel_launch(void* const* d_in, const int* in_sizes, int n_in,
                              void* d_out, int out_size, void* d_ws, size_t ws_size,
                              hipStream_t stream) {
  const float* x    = (const float*)d_in[0];
  const float* Watt = (const float*)d_in[1];
  const float* We   = (const float*)d_in[3];
  const float* be   = (const float*)d_in[4];
  const float* Wse  = (const float*)d_in[5];
  const float* bse  = (const float*)d_in[6];
  const float* Wg   = (const float*)d_in[7];
  const float* bg   = (const float*)d_in[8];
  const float* Wo   = (const float*)d_in[9];
  const float* bo   = (const float*)d_in[10];
  float* out = (float*)d_out;
  float* ws  = (float*)d_ws;
  const int B = in_sizes[0] / OBS;

  setup_kernel<<<66, 256, 0, stream>>>(Watt, We, be, Wse, bse, Wg, bg, Wo, bo, ws);
  pool_kernel<<<NWAVES / 4, 256, 0, stream>>>(x, ws, out, B);
  proj_kernel<<<B / PR_ROWS, 256, 0, stream>>>(ws, out);
}